// Round 1
// baseline (10093.246 us; speedup 1.0000x reference)
//
#include <hip/hip_runtime.h>

typedef unsigned long long u64;
typedef unsigned int u32;

static constexpr int BROWS = 4096;   // batch rows (M)
static constexpr int ENUM_ = 16384;  // num embeddings (N)
static constexpr int KD    = 4096;   // embedding dim (K)

// ---------- helpers ----------

// map float -> u32 such that unsigned compare == float compare (ascending)
__device__ __forceinline__ u32 sortable(float d) {
  u32 u = __float_as_uint(d);
  return (u & 0x80000000u) ? ~u : (u | 0x80000000u);
}

__device__ __forceinline__ float blockReduceSumF(float v) {
  __shared__ float s[4];
  #pragma unroll
  for (int o = 32; o > 0; o >>= 1) v += __shfl_down(v, o);
  int lane = threadIdx.x & 63, wid = threadIdx.x >> 6;
  if (lane == 0) s[wid] = v;
  __syncthreads();
  float r = 0.f;
  if (threadIdx.x == 0) r = s[0] + s[1] + s[2] + s[3];
  return r;
}

__device__ __forceinline__ double blockReduceSumD(double v) {
  __shared__ double s[4];
  #pragma unroll
  for (int o = 32; o > 0; o >>= 1) v += __shfl_down(v, o);
  int lane = threadIdx.x & 63, wid = threadIdx.x >> 6;
  if (lane == 0) s[wid] = v;
  __syncthreads();
  double r = 0.0;
  if (threadIdx.x == 0) r = s[0] + s[1] + s[2] + s[3];
  return r;
}

// ---------- kernels ----------

// e2[j] = sum_k w[j][k]^2   (one block per embedding row)
__global__ __launch_bounds__(256) void e2_kernel(const float* __restrict__ w,
                                                 float* __restrict__ e2) {
  int j = blockIdx.x;
  const float4* wr = (const float4*)(w + (size_t)j * KD);
  float local = 0.f;
  #pragma unroll
  for (int t = 0; t < 4; ++t) {
    float4 v = wr[threadIdx.x + t * 256];
    local += v.x * v.x + v.y * v.y + v.z * v.z + v.w * v.w;
  }
  float tot = blockReduceSumF(local);
  if (threadIdx.x == 0) e2[j] = tot;
}

// Fused SGEMM + argmin. C[i][j] = x_i . w_j ; d = e2[j] - 2*C  (row-constant
// ||x||^2 omitted: argmin-invariant, and adding it would quantize distances
// at ulp(4096)=4.9e-4, comparable to the ~1.1e-3 top-2 gap).
// 128x128 tile, BK=8, 256 threads, 8x8 per thread.
// blockIdx.x = M-tile (fast-varying -> consecutive blocks share B panel in L2)
// blockIdx.y = N-tile
__global__ __launch_bounds__(256)
void gemm_argmin(const float* __restrict__ A,   // [BROWS][KD] inputs
                 const float* __restrict__ W,   // [ENUM_][KD] embed
                 const float* __restrict__ e2,  // [ENUM_]
                 u64* __restrict__ best) {      // [BROWS] packed (key,col)
  __shared__ union {
    struct { float As[8][128]; float Bs[8][128]; } st;
    u64 red[128 * 16];
  } sm;

  const int by = blockIdx.x;            // 0..31  (M tiles)
  const int bx = blockIdx.y;            // 0..127 (N tiles)
  const int tid = threadIdx.x;
  const int tx = tid & 15, ty = tid >> 4;
  const int row0 = by * 128, col0 = bx * 128;

  // staging: each thread loads one float4 of A and one of B per K-step
  const int lm = tid >> 1;              // 0..127 (tile row)
  const int lk = (tid & 1) * 4;         // 0 or 4 (k offset)
  const float* Ap = A + (size_t)(row0 + lm) * KD + lk;
  const float* Wp = W + (size_t)(col0 + lm) * KD + lk;

  float acc[8][8];
  #pragma unroll
  for (int r = 0; r < 8; ++r)
    #pragma unroll
    for (int c = 0; c < 8; ++c) acc[r][c] = 0.f;

  for (int kk = 0; kk < KD; kk += 8) {
    float4 av = *(const float4*)(Ap + kk);
    float4 bv = *(const float4*)(Wp + kk);
    __syncthreads();  // previous compute done before overwriting LDS
    sm.st.As[lk + 0][lm] = av.x;
    sm.st.As[lk + 1][lm] = av.y;
    sm.st.As[lk + 2][lm] = av.z;
    sm.st.As[lk + 3][lm] = av.w;
    sm.st.Bs[lk + 0][lm] = bv.x;
    sm.st.Bs[lk + 1][lm] = bv.y;
    sm.st.Bs[lk + 2][lm] = bv.z;
    sm.st.Bs[lk + 3][lm] = bv.w;
    __syncthreads();
    #pragma unroll
    for (int k = 0; k < 8; ++k) {
      float a[8], b[8];
      *(float4*)&a[0] = *(const float4*)&sm.st.As[k][ty * 8];
      *(float4*)&a[4] = *(const float4*)&sm.st.As[k][ty * 8 + 4];
      *(float4*)&b[0] = *(const float4*)&sm.st.Bs[k][tx * 8];
      *(float4*)&b[4] = *(const float4*)&sm.st.Bs[k][tx * 8 + 4];
      #pragma unroll
      for (int r = 0; r < 8; ++r)
        #pragma unroll
        for (int c = 0; c < 8; ++c)
          acc[r][c] = fmaf(a[r], b[c], acc[r][c]);
    }
  }

  __syncthreads();  // done reading As/Bs; LDS is reused for reduction

  float e2v[8];
  #pragma unroll
  for (int c = 0; c < 8; ++c) e2v[c] = e2[col0 + tx * 8 + c];

  #pragma unroll
  for (int r = 0; r < 8; ++r) {
    u64 bk = ~0ull;
    #pragma unroll
    for (int c = 0; c < 8; ++c) {
      int col = col0 + tx * 8 + c;
      float d = fmaf(-2.0f, acc[r][c], e2v[c]);
      u64 key = ((u64)sortable(d) << 32) | (u32)col;  // tie -> smaller col
      bk = key < bk ? key : bk;
    }
    sm.red[(ty * 8 + r) * 16 + tx] = bk;
  }
  __syncthreads();
  if (tid < 128) {
    u64 m = sm.red[tid * 16];
    #pragma unroll
    for (int t = 1; t < 16; ++t) {
      u64 v = sm.red[tid * 16 + t];
      m = v < m ? v : m;
    }
    atomicMin(&best[row0 + tid], m);
  }
}

// per-row: extract index, histogram, write one-hot 1.0
__global__ __launch_bounds__(256) void scatter_kernel(const u64* __restrict__ best,
                                                      int* __restrict__ idx,
                                                      int* __restrict__ counts,
                                                      float* __restrict__ enc) {
  int i = blockIdx.x * 256 + threadIdx.x;  // 0..4095
  u64 k = best[i];
  int j = (int)(k & 0xffffffffu);
  idx[i] = j;
  atomicAdd(&counts[j], 1);
  enc[(size_t)i * ENUM_ + j] = 1.0f;
}

// quantized[i][:] = w[idx[i]][:]  (straight-through value == codebook row),
// loss partial sum of (q - x)^2 in fp64. One block per row.
// NOTE: quant base is d_out+1 (odd float offset) -> scalar stores only.
__global__ __launch_bounds__(256) void gather_loss(const float* __restrict__ x,
                                                   const float* __restrict__ w,
                                                   const int* __restrict__ idx,
                                                   float* __restrict__ quant,
                                                   double* __restrict__ accum) {
  int i = blockIdx.x;
  int j = idx[i];
  const float4* wr = (const float4*)(w + (size_t)j * KD);
  const float4* xr = (const float4*)(x + (size_t)i * KD);
  float* qr = quant + (size_t)i * KD;
  double local = 0.0;
  #pragma unroll
  for (int t = 0; t < 4; ++t) {
    int e = threadIdx.x + t * 256;       // float4 index within row
    float4 wv = wr[e];
    float4 xv = xr[e];
    qr[4 * e + 0] = wv.x;
    qr[4 * e + 1] = wv.y;
    qr[4 * e + 2] = wv.z;
    qr[4 * e + 3] = wv.w;
    double d0 = (double)wv.x - (double)xv.x;
    double d1 = (double)wv.y - (double)xv.y;
    double d2 = (double)wv.z - (double)xv.z;
    double d3 = (double)wv.w - (double)xv.w;
    local += d0 * d0 + d1 * d1 + d2 * d2 + d3 * d3;
  }
  double tot = blockReduceSumD(local);
  if (threadIdx.x == 0) atomicAdd(accum, tot);
}

// loss + perplexity scalars (single block)
__global__ __launch_bounds__(256) void scalars_kernel(const int* __restrict__ counts,
                                                      const double* __restrict__ accum,
                                                      float* __restrict__ loss_out,
                                                      float* __restrict__ perp_out) {
  double local = 0.0;
  for (int j = threadIdx.x; j < ENUM_; j += 256) {
    double p = (double)counts[j] * (1.0 / 4096.0);
    local += p * log(p + 1e-10);
  }
  double s = blockReduceSumD(local);  // = sum p*log(p+eps)
  if (threadIdx.x == 0) {
    double mean = (*accum) * (1.0 / ((double)BROWS * (double)KD));
    loss_out[0] = (float)(1.25 * mean);   // q_latent + 0.25*e_latent
    perp_out[0] = (float)exp(-s);
  }
}

// ---------- launch ----------

extern "C" void kernel_launch(void* const* d_in, const int* in_sizes, int n_in,
                              void* d_out, int out_size, void* d_ws, size_t ws_size,
                              hipStream_t stream) {
  const float* x = (const float*)d_in[0];  // [4096,64,4,4,4] = [4096][4096]
  const float* w = (const float*)d_in[1];  // [16384][4096]
  float* out = (float*)d_out;

  char* ws = (char*)d_ws;
  u64* best    = (u64*)ws;                 // 4096 * 8  = 32768
  int* idx     = (int*)(ws + 32768);       // 4096 * 4  = 16384
  int* counts  = (int*)(ws + 49152);       // 16384 * 4 = 65536
  double* accum = (double*)(ws + 114688);  // 8
  float* e2    = (float*)(ws + 131072);    // 16384 * 4 = 65536

  // d_out layout: [loss(1)] [quantized(16777216)] [perplexity(1)] [encodings(67108864)]
  float* loss_out = out;
  float* quant    = out + 1;
  float* perp_out = out + 16777217;
  float* enc      = out + 16777218;

  hipMemsetAsync(best, 0xFF, 4096 * sizeof(u64), stream);           // +inf keys
  hipMemsetAsync(counts, 0, 65536 + 8, stream);                     // counts + accum
  hipMemsetAsync(enc, 0, (size_t)BROWS * ENUM_ * sizeof(float), stream);

  e2_kernel<<<ENUM_, 256, 0, stream>>>(w, e2);
  gemm_argmin<<<dim3(32, 128), 256, 0, stream>>>(x, w, e2, best);
  scatter_kernel<<<BROWS / 256, 256, 0, stream>>>(best, idx, counts, enc);
  gather_loss<<<BROWS, 256, 0, stream>>>(x, w, idx, quant, accum);
  scalars_kernel<<<1, 256, 0, stream>>>(counts, accum, loss_out, perp_out);
}

// Round 2
// 2296.019 us; speedup vs baseline: 4.3960x; 4.3960x over previous
//
#include <hip/hip_runtime.h>

typedef unsigned long long u64;
typedef unsigned int u32;
typedef unsigned short u16;

typedef __attribute__((ext_vector_type(8))) short short8;
typedef __attribute__((ext_vector_type(4))) float floatx4;

static constexpr int BROWS = 4096;   // batch rows (M)
static constexpr int ENUM_ = 16384;  // num embeddings (N)
static constexpr int KD    = 4096;   // embedding dim (K)

// ---------- helpers ----------

// map float -> u32 such that unsigned compare == float compare (ascending)
__device__ __forceinline__ u32 sortable(float d) {
  u32 u = __float_as_uint(d);
  return (u & 0x80000000u) ? ~u : (u | 0x80000000u);
}

__device__ __forceinline__ u16 f2bf_rn(float f) {
  u32 u = __float_as_uint(f);
  u32 r = (u + 0x7fffu + ((u >> 16) & 1u)) >> 16;   // RNE (no NaNs in data)
  return (u16)r;
}
__device__ __forceinline__ float bf2f(u16 h) {
  return __uint_as_float((u32)h << 16);
}

__device__ __forceinline__ void gload_lds16(const void* g, void* l) {
  __builtin_amdgcn_global_load_lds((const __attribute__((address_space(1))) void*)g,
                                   (__attribute__((address_space(3))) void*)l,
                                   16, 0, 0);
}

__device__ __forceinline__ float blockReduceSumF(float v) {
  __shared__ float s[4];
  #pragma unroll
  for (int o = 32; o > 0; o >>= 1) v += __shfl_down(v, o);
  int lane = threadIdx.x & 63, wid = threadIdx.x >> 6;
  if (lane == 0) s[wid] = v;
  __syncthreads();
  float r = 0.f;
  if (threadIdx.x == 0) r = s[0] + s[1] + s[2] + s[3];
  return r;
}

__device__ __forceinline__ double blockReduceSumD(double v) {
  __shared__ double s[4];
  #pragma unroll
  for (int o = 32; o > 0; o >>= 1) v += __shfl_down(v, o);
  int lane = threadIdx.x & 63, wid = threadIdx.x >> 6;
  if (lane == 0) s[wid] = v;
  __syncthreads();
  double r = 0.0;
  if (threadIdx.x == 0) r = s[0] + s[1] + s[2] + s[3];
  return r;
}

// ---------- precompute kernels ----------

// e2[j] = sum_k w[j][k]^2 from ORIGINAL fp32 (one block per embedding row)
__global__ __launch_bounds__(256) void e2_kernel(const float* __restrict__ w,
                                                 float* __restrict__ e2) {
  int j = blockIdx.x;
  const float4* wr = (const float4*)(w + (size_t)j * KD);
  float local = 0.f;
  #pragma unroll
  for (int t = 0; t < 4; ++t) {
    float4 v = wr[threadIdx.x + t * 256];
    local += v.x * v.x + v.y * v.y + v.z * v.z + v.w * v.w;
  }
  float tot = blockReduceSumF(local);
  if (threadIdx.x == 0) e2[j] = tot;
}

// split fp32 -> bf16 hi + bf16 lo (8 elems / thread)
__global__ __launch_bounds__(256) void split_kernel(const float* __restrict__ src,
                                                    u16* __restrict__ hi,
                                                    u16* __restrict__ lo,
                                                    int n8) {
  int t = blockIdx.x * 256 + threadIdx.x;
  if (t >= n8) return;
  const float4* s = (const float4*)src + (size_t)t * 2;
  float4 a = s[0], b = s[1];
  float v[8] = {a.x, a.y, a.z, a.w, b.x, b.y, b.z, b.w};
  short h[8], l[8];
  #pragma unroll
  for (int i = 0; i < 8; ++i) {
    u16 hh = f2bf_rn(v[i]);
    h[i] = (short)hh;
    l[i] = (short)f2bf_rn(v[i] - bf2f(hh));
  }
  *(short8*)(hi + (size_t)t * 8) = *(short8*)h;
  *(short8*)(lo + (size_t)t * 8) = *(short8*)l;
}

// ---------- MFMA GEMM + argmin ----------
// s_ij = x_i . w_j computed as Ah*Bh + Al*Bh + Ah*Bl (lo*lo dropped, ~1e-8 err)
// key = e2[j] - 2*s (row-constant ||x||^2 omitted: argmin-invariant).
// 128x128 tile, BK=32, 256 threads = 4 waves in 2x2, 4x4 16x16x32 frags/wave.
// LDS chunk swizzle: slot s holds global 16B-chunk s ^ ((row>>1)&3)  -> 2-way
// granule aliasing only (free).
__global__ __launch_bounds__(256)
void gemm_argmin_mfma(const u16* __restrict__ Ah, const u16* __restrict__ Al,
                      const u16* __restrict__ Bh, const u16* __restrict__ Bl,
                      const float* __restrict__ e2, u64* __restrict__ best) {
  __shared__ char smem[32768];   // Ah|Al|Bh|Bl tiles, 8 KB each (128 rows x 64 B)

  const int by = blockIdx.x;     // M tile (fast -> consecutive blocks share B)
  const int bx = blockIdx.y;     // N tile
  const int row0 = by * 128, col0 = bx * 128;
  const int t = threadIdx.x;
  const int lane = t & 63, wv = t >> 6;
  const int wr = wv >> 1, wc = wv & 1;

  // staging: thread t covers rows (t>>2) and (t>>2)+64, 16B chunk (t&3);
  // source chunk is swizzled so LDS[row][slot] = G[row][slot ^ ((row>>1)&3)]
  const int srow = t >> 2;
  const int schunk = (t & 3) ^ ((t >> 3) & 3);
  const size_t aoff0 = (size_t)(row0 + srow) * KD + schunk * 8;
  const size_t aoff1 = aoff0 + (size_t)64 * KD;
  const size_t boff0 = (size_t)(col0 + srow) * KD + schunk * 8;
  const size_t boff1 = boff0 + (size_t)64 * KD;

  char* sAh = smem;
  char* sAl = smem + 8192;
  char* sBh = smem + 16384;
  char* sBl = smem + 24576;
  const int d0 = t * 16;        // LDS dest for it=0 (wave-uniform base + lane*16)
  const int d1 = 4096 + t * 16; // it=1

  floatx4 acc[4][4] = {};

  for (int kk = 0; kk < KD; kk += 32) {
    __syncthreads();  // previous compute done before overwriting LDS
    gload_lds16(Ah + aoff0 + kk, sAh + d0);
    gload_lds16(Ah + aoff1 + kk, sAh + d1);
    gload_lds16(Al + aoff0 + kk, sAl + d0);
    gload_lds16(Al + aoff1 + kk, sAl + d1);
    gload_lds16(Bh + boff0 + kk, sBh + d0);
    gload_lds16(Bh + boff1 + kk, sBh + d1);
    gload_lds16(Bl + boff0 + kk, sBl + d0);
    gload_lds16(Bl + boff1 + kk, sBl + d1);
    __syncthreads();  // compiler drains vmcnt before s_barrier

    short8 afh[4], afl[4];
    #pragma unroll
    for (int r = 0; r < 4; ++r) {
      int m = wr * 64 + r * 16 + (lane & 15);
      int off = m * 64 + (((lane >> 4) ^ ((m >> 1) & 3)) * 16);
      afh[r] = *(const short8*)(sAh + off);
      afl[r] = *(const short8*)(sAl + off);
    }
    #pragma unroll
    for (int c = 0; c < 4; ++c) {
      int m = wc * 64 + c * 16 + (lane & 15);
      int off = m * 64 + (((lane >> 4) ^ ((m >> 1) & 3)) * 16);
      short8 bfh = *(const short8*)(sBh + off);
      short8 bfl = *(const short8*)(sBl + off);
      #pragma unroll
      for (int r = 0; r < 4; ++r) {
        acc[r][c] = __builtin_amdgcn_mfma_f32_16x16x32_bf16(afh[r], bfh, acc[r][c], 0, 0, 0);
        acc[r][c] = __builtin_amdgcn_mfma_f32_16x16x32_bf16(afl[r], bfh, acc[r][c], 0, 0, 0);
        acc[r][c] = __builtin_amdgcn_mfma_f32_16x16x32_bf16(afh[r], bfl, acc[r][c], 0, 0, 0);
      }
    }
  }

  // epilogue: C/D layout col=lane&15, row=(lane>>4)*4+reg
  const int quad = lane >> 4, lcol = lane & 15;
  float e2v[4];
  #pragma unroll
  for (int c = 0; c < 4; ++c) e2v[c] = e2[col0 + wc * 64 + c * 16 + lcol];

  #pragma unroll
  for (int r = 0; r < 4; ++r) {
    #pragma unroll
    for (int i = 0; i < 4; ++i) {
      int grow = row0 + wr * 64 + r * 16 + quad * 4 + i;
      u64 kmin = ~0ull;
      #pragma unroll
      for (int c = 0; c < 4; ++c) {
        int gcol = col0 + wc * 64 + c * 16 + lcol;
        float d = __fadd_rn(e2v[c], __fmul_rn(-2.0f, acc[r][c][i]));
        u64 key = ((u64)sortable(d) << 32) | (u32)gcol;  // tie -> smaller col
        kmin = key < kmin ? key : kmin;
      }
      #pragma unroll
      for (int msk = 1; msk < 16; msk <<= 1) {
        u64 o = __shfl_xor(kmin, msk);
        kmin = o < kmin ? o : kmin;
      }
      if (lcol == 0) atomicMin(&best[grow], kmin);
    }
  }
}

// ---------- fp32 fallback GEMM (round-1 kernel, used if ws too small) ----------
__global__ __launch_bounds__(256)
void gemm_argmin(const float* __restrict__ A, const float* __restrict__ W,
                 const float* __restrict__ e2, u64* __restrict__ best) {
  __shared__ union {
    struct { float As[8][128]; float Bs[8][128]; } st;
    u64 red[128 * 16];
  } sm;
  const int by = blockIdx.x, bx = blockIdx.y;
  const int tid = threadIdx.x;
  const int tx = tid & 15, ty = tid >> 4;
  const int row0 = by * 128, col0 = bx * 128;
  const int lm = tid >> 1, lk = (tid & 1) * 4;
  const float* Ap = A + (size_t)(row0 + lm) * KD + lk;
  const float* Wp = W + (size_t)(col0 + lm) * KD + lk;
  float acc[8][8];
  #pragma unroll
  for (int r = 0; r < 8; ++r)
    #pragma unroll
    for (int c = 0; c < 8; ++c) acc[r][c] = 0.f;
  for (int kk = 0; kk < KD; kk += 8) {
    float4 av = *(const float4*)(Ap + kk);
    float4 bv = *(const float4*)(Wp + kk);
    __syncthreads();
    sm.st.As[lk + 0][lm] = av.x; sm.st.As[lk + 1][lm] = av.y;
    sm.st.As[lk + 2][lm] = av.z; sm.st.As[lk + 3][lm] = av.w;
    sm.st.Bs[lk + 0][lm] = bv.x; sm.st.Bs[lk + 1][lm] = bv.y;
    sm.st.Bs[lk + 2][lm] = bv.z; sm.st.Bs[lk + 3][lm] = bv.w;
    __syncthreads();
    #pragma unroll
    for (int k = 0; k < 8; ++k) {
      float a[8], b[8];
      *(float4*)&a[0] = *(const float4*)&sm.st.As[k][ty * 8];
      *(float4*)&a[4] = *(const float4*)&sm.st.As[k][ty * 8 + 4];
      *(float4*)&b[0] = *(const float4*)&sm.st.Bs[k][tx * 8];
      *(float4*)&b[4] = *(const float4*)&sm.st.Bs[k][tx * 8 + 4];
      #pragma unroll
      for (int r = 0; r < 8; ++r)
        #pragma unroll
        for (int c = 0; c < 8; ++c)
          acc[r][c] = fmaf(a[r], b[c], acc[r][c]);
    }
  }
  __syncthreads();
  float e2v[8];
  #pragma unroll
  for (int c = 0; c < 8; ++c) e2v[c] = e2[col0 + tx * 8 + c];
  #pragma unroll
  for (int r = 0; r < 8; ++r) {
    u64 bk = ~0ull;
    #pragma unroll
    for (int c = 0; c < 8; ++c) {
      int col = col0 + tx * 8 + c;
      float d = fmaf(-2.0f, acc[r][c], e2v[c]);
      u64 key = ((u64)sortable(d) << 32) | (u32)col;
      bk = key < bk ? key : bk;
    }
    sm.red[(ty * 8 + r) * 16 + tx] = bk;
  }
  __syncthreads();
  if (tid < 128) {
    u64 m = sm.red[tid * 16];
    #pragma unroll
    for (int t2 = 1; t2 < 16; ++t2) {
      u64 v = sm.red[tid * 16 + t2];
      m = v < m ? v : m;
    }
    atomicMin(&best[row0 + tid], m);
  }
}

// ---------- tail kernels ----------

__global__ __launch_bounds__(256) void scatter_kernel(const u64* __restrict__ best,
                                                      int* __restrict__ idx,
                                                      int* __restrict__ counts,
                                                      float* __restrict__ enc) {
  int i = blockIdx.x * 256 + threadIdx.x;
  u64 k = best[i];
  int j = (int)(k & 0xffffffffu);
  idx[i] = j;
  atomicAdd(&counts[j], 1);
  enc[(size_t)i * ENUM_ + j] = 1.0f;
}

__global__ __launch_bounds__(256) void gather_loss(const float* __restrict__ x,
                                                   const float* __restrict__ w,
                                                   const int* __restrict__ idx,
                                                   float* __restrict__ quant,
                                                   double* __restrict__ accum) {
  int i = blockIdx.x;
  int j = idx[i];
  const float4* wr = (const float4*)(w + (size_t)j * KD);
  const float4* xr = (const float4*)(x + (size_t)i * KD);
  float* qr = quant + (size_t)i * KD;
  double local = 0.0;
  #pragma unroll
  for (int t = 0; t < 4; ++t) {
    int e = threadIdx.x + t * 256;
    float4 wv = wr[e];
    float4 xv = xr[e];
    qr[4 * e + 0] = wv.x; qr[4 * e + 1] = wv.y;
    qr[4 * e + 2] = wv.z; qr[4 * e + 3] = wv.w;
    double d0 = (double)wv.x - (double)xv.x;
    double d1 = (double)wv.y - (double)xv.y;
    double d2 = (double)wv.z - (double)xv.z;
    double d3 = (double)wv.w - (double)xv.w;
    local += d0 * d0 + d1 * d1 + d2 * d2 + d3 * d3;
  }
  double tot = blockReduceSumD(local);
  if (threadIdx.x == 0) atomicAdd(accum, tot);
}

__global__ __launch_bounds__(256) void scalars_kernel(const int* __restrict__ counts,
                                                      const double* __restrict__ accum,
                                                      float* __restrict__ loss_out,
                                                      float* __restrict__ perp_out) {
  double local = 0.0;
  for (int j = threadIdx.x; j < ENUM_; j += 256) {
    double p = (double)counts[j] * (1.0 / 4096.0);
    local += p * log(p + 1e-10);
  }
  double s = blockReduceSumD(local);
  if (threadIdx.x == 0) {
    double mean = (*accum) * (1.0 / ((double)BROWS * (double)KD));
    loss_out[0] = (float)(1.25 * mean);
    perp_out[0] = (float)exp(-s);
  }
}

// ---------- launch ----------

extern "C" void kernel_launch(void* const* d_in, const int* in_sizes, int n_in,
                              void* d_out, int out_size, void* d_ws, size_t ws_size,
                              hipStream_t stream) {
  const float* x = (const float*)d_in[0];  // [4096][4096]
  const float* w = (const float*)d_in[1];  // [16384][4096]
  float* out = (float*)d_out;

  char* ws = (char*)d_ws;
  u64* best     = (u64*)ws;                // 32768
  int* idx      = (int*)(ws + 32768);      // 16384
  int* counts   = (int*)(ws + 49152);      // 65536
  double* accum = (double*)(ws + 114688);  // 8
  float* e2     = (float*)(ws + 131072);   // 65536
  u16* x_hi     = (u16*)(ws + 196608);                // 33554432
  u16* x_lo     = (u16*)(ws + 196608 + 33554432ull);  // 33554432
  u16* w_hi     = (u16*)(ws + 196608 + 67108864ull);  // 134217728
  u16* w_lo     = (u16*)(ws + 196608 + 201326592ull); // 134217728
  const size_t NEED = 196608ull + 2 * 33554432ull + 2 * 134217728ull;

  float* loss_out = out;
  float* quant    = out + 1;
  float* perp_out = out + 16777217;
  float* enc      = out + 16777218;

  hipMemsetAsync(best, 0xFF, 4096 * sizeof(u64), stream);
  hipMemsetAsync(counts, 0, 65536 + 8, stream);
  hipMemsetAsync(enc, 0, (size_t)BROWS * ENUM_ * sizeof(float), stream);

  e2_kernel<<<ENUM_, 256, 0, stream>>>(w, e2);
  if (ws_size >= NEED) {
    split_kernel<<<BROWS * KD / 8 / 256, 256, 0, stream>>>(x, x_hi, x_lo, BROWS * KD / 8);
    split_kernel<<<ENUM_ * KD / 8 / 256, 256, 0, stream>>>(w, w_hi, w_lo, ENUM_ * KD / 8);
    gemm_argmin_mfma<<<dim3(32, 128), 256, 0, stream>>>(x_hi, x_lo, w_hi, w_lo, e2, best);
  } else {
    gemm_argmin<<<dim3(32, 128), 256, 0, stream>>>(x, w, e2, best);
  }
  scatter_kernel<<<BROWS / 256, 256, 0, stream>>>(best, idx, counts, enc);
  gather_loss<<<BROWS, 256, 0, stream>>>(x, w, idx, quant, accum);
  scalars_kernel<<<1, 256, 0, stream>>>(counts, accum, loss_out, perp_out);
}

// Round 3
// 1371.471 us; speedup vs baseline: 7.3594x; 1.6741x over previous
//
#include <hip/hip_runtime.h>

typedef unsigned long long u64;
typedef unsigned int u32;
typedef unsigned short u16;

typedef __attribute__((ext_vector_type(8))) short short8;
typedef __attribute__((ext_vector_type(4))) short short4v;
typedef __attribute__((ext_vector_type(4))) float floatx4;

static constexpr int BROWS = 4096;   // batch rows (M)
static constexpr int ENUM_ = 16384;  // num embeddings (N)
static constexpr int KD    = 4096;   // embedding dim (K)
static constexpr int CANDMAX = 65536;
#define MARGIN 4e-4f

// ---------- helpers ----------

__device__ __forceinline__ u32 sortable(float d) {
  u32 u = __float_as_uint(d);
  return (u & 0x80000000u) ? ~u : (u | 0x80000000u);
}
__device__ __forceinline__ float unsortable(u32 k) {
  u32 u = (k & 0x80000000u) ? (k & 0x7fffffffu) : ~k;
  return __uint_as_float(u);
}

__device__ __forceinline__ u16 f2bf_rn(float f) {
  u32 u = __float_as_uint(f);
  u32 r = (u + 0x7fffu + ((u >> 16) & 1u)) >> 16;   // RNE (no NaNs in data)
  return (u16)r;
}
__device__ __forceinline__ float bf2f(u16 h) {
  return __uint_as_float((u32)h << 16);
}

__device__ __forceinline__ void gload_lds16(const void* g, void* l) {
  __builtin_amdgcn_global_load_lds((const __attribute__((address_space(1))) void*)g,
                                   (__attribute__((address_space(3))) void*)l,
                                   16, 0, 0);
}

__device__ __forceinline__ float blockReduceSumF(float v) {
  __shared__ float s[4];
  #pragma unroll
  for (int o = 32; o > 0; o >>= 1) v += __shfl_down(v, o);
  int lane = threadIdx.x & 63, wid = threadIdx.x >> 6;
  if (lane == 0) s[wid] = v;
  __syncthreads();
  float r = 0.f;
  if (threadIdx.x == 0) r = s[0] + s[1] + s[2] + s[3];
  return r;
}

__device__ __forceinline__ double blockReduceSumD(double v) {
  __shared__ double s[4];
  #pragma unroll
  for (int o = 32; o > 0; o >>= 1) v += __shfl_down(v, o);
  int lane = threadIdx.x & 63, wid = threadIdx.x >> 6;
  if (lane == 0) s[wid] = v;
  __syncthreads();
  double r = 0.0;
  if (threadIdx.x == 0) r = s[0] + s[1] + s[2] + s[3];
  return r;
}

// ---------- precompute kernels ----------

// x: fp32 -> bf16 hi only (8 elems / thread)
__global__ __launch_bounds__(256) void split_hi(const float* __restrict__ src,
                                                u16* __restrict__ hi, int n8) {
  int t = blockIdx.x * 256 + threadIdx.x;
  if (t >= n8) return;
  const float4* s = (const float4*)src + (size_t)t * 2;
  float4 a = s[0], b = s[1];
  float v[8] = {a.x, a.y, a.z, a.w, b.x, b.y, b.z, b.w};
  short h[8];
  #pragma unroll
  for (int i = 0; i < 8; ++i) h[i] = (short)f2bf_rn(v[i]);
  *(short8*)(hi + (size_t)t * 8) = *(short8*)h;
}

// w: fp32 -> bf16 hi, fused with e2[j]=sum w^2 (fp32, same tree as round 2).
// one block per embedding row.
__global__ __launch_bounds__(256) void split_w_e2(const float* __restrict__ w,
                                                  u16* __restrict__ hi,
                                                  float* __restrict__ e2) {
  int j = blockIdx.x;
  const float4* wr = (const float4*)(w + (size_t)j * KD);
  u16* hr = hi + (size_t)j * KD;
  float local = 0.f;
  #pragma unroll
  for (int t = 0; t < 4; ++t) {
    int e = threadIdx.x + t * 256;
    float4 v = wr[e];
    local += v.x * v.x + v.y * v.y + v.z * v.z + v.w * v.w;
    short h[4] = {(short)f2bf_rn(v.x), (short)f2bf_rn(v.y),
                  (short)f2bf_rn(v.z), (short)f2bf_rn(v.w)};
    *(short4v*)(hr + (size_t)e * 4) = *(short4v*)h;
  }
  float tot = blockReduceSumF(local);
  if (threadIdx.x == 0) e2[j] = tot;
}

// fp32 -> bf16 hi + lo (for 3-term fallback)
__global__ __launch_bounds__(256) void split_kernel(const float* __restrict__ src,
                                                    u16* __restrict__ hi,
                                                    u16* __restrict__ lo, int n8) {
  int t = blockIdx.x * 256 + threadIdx.x;
  if (t >= n8) return;
  const float4* s = (const float4*)src + (size_t)t * 2;
  float4 a = s[0], b = s[1];
  float v[8] = {a.x, a.y, a.z, a.w, b.x, b.y, b.z, b.w};
  short h[8], l[8];
  #pragma unroll
  for (int i = 0; i < 8; ++i) {
    u16 hh = f2bf_rn(v[i]);
    h[i] = (short)hh;
    l[i] = (short)f2bf_rn(v[i] - bf2f(hh));
  }
  *(short8*)(hi + (size_t)t * 8) = *(short8*)h;
  *(short8*)(lo + (size_t)t * 8) = *(short8*)l;
}

// e2 standalone (fallback paths)
__global__ __launch_bounds__(256) void e2_kernel(const float* __restrict__ w,
                                                 float* __restrict__ e2) {
  int j = blockIdx.x;
  const float4* wr = (const float4*)(w + (size_t)j * KD);
  float local = 0.f;
  #pragma unroll
  for (int t = 0; t < 4; ++t) {
    float4 v = wr[threadIdx.x + t * 256];
    local += v.x * v.x + v.y * v.y + v.z * v.z + v.w * v.w;
  }
  float tot = blockReduceSumF(local);
  if (threadIdx.x == 0) e2[j] = tot;
}

// ---------- pass 1: hi*hi MFMA GEMM, store d-hat + per-row min ----------
// 128x128 tile, BK=64, 256 threads = 4 waves 2x2, 4x4 16x16x32 frags/wave.
// LDS rows are 128 B (8 x 16B slots); slot s of row m holds global chunk
// s ^ (m&7) -> frag reads are 2-way-aliased only (free per m136).
__global__ __launch_bounds__(256)
void gemm_hi(const u16* __restrict__ Ah, const u16* __restrict__ Bh,
             const float* __restrict__ e2, float* __restrict__ dist,
             u64* __restrict__ best) {
  __shared__ char smem[32768];   // sA 16 KB | sB 16 KB

  const int by = blockIdx.x;     // M tile (fast -> consecutive blocks share B)
  const int bx = blockIdx.y;     // N tile
  const int row0 = by * 128, col0 = bx * 128;
  const int t = threadIdx.x;
  const int lane = t & 63, wv = t >> 6;
  const int wr = wv >> 1, wc = wv & 1;
  const int quad = lane >> 4, lcol = lane & 15;

  char* sA = smem;
  char* sB = smem + 16384;

  floatx4 acc[4][4] = {};

  for (int kk = 0; kk < KD; kk += 64) {
    __syncthreads();  // previous compute done before overwriting LDS
    #pragma unroll
    for (int i2 = 0; i2 < 4; ++i2) {
      int c = t + i2 * 256;            // 16B chunk id, 0..1023
      int row = c >> 3, slot = c & 7;
      int g = slot ^ (row & 7);        // source chunk (swizzled)
      gload_lds16(Ah + (size_t)(row0 + row) * KD + kk + g * 8, sA + c * 16);
      gload_lds16(Bh + (size_t)(col0 + row) * KD + kk + g * 8, sB + c * 16);
    }
    __syncthreads();

    short8 af[4][2];
    #pragma unroll
    for (int r = 0; r < 4; ++r) {
      int m = wr * 64 + r * 16 + lcol;
      #pragma unroll
      for (int kw = 0; kw < 2; ++kw) {
        int off = m * 128 + (((kw << 2) | quad) ^ (m & 7)) * 16;
        af[r][kw] = *(const short8*)(sA + off);
      }
    }
    #pragma unroll
    for (int c = 0; c < 4; ++c) {
      int m = wc * 64 + c * 16 + lcol;
      int off0 = m * 128 + ((quad) ^ (m & 7)) * 16;
      int off1 = m * 128 + ((4 | quad) ^ (m & 7)) * 16;
      short8 bf0 = *(const short8*)(sB + off0);
      short8 bf1 = *(const short8*)(sB + off1);
      #pragma unroll
      for (int r = 0; r < 4; ++r) {
        acc[r][c] = __builtin_amdgcn_mfma_f32_16x16x32_bf16(af[r][0], bf0, acc[r][c], 0, 0, 0);
        acc[r][c] = __builtin_amdgcn_mfma_f32_16x16x32_bf16(af[r][1], bf1, acc[r][c], 0, 0, 0);
      }
    }
  }

  // epilogue: C/D layout col=lane&15, row=(lane>>4)*4+reg
  float e2v[4];
  #pragma unroll
  for (int c = 0; c < 4; ++c) e2v[c] = e2[col0 + wc * 64 + c * 16 + lcol];

  #pragma unroll
  for (int r = 0; r < 4; ++r) {
    #pragma unroll
    for (int i = 0; i < 4; ++i) {
      int grow = row0 + wr * 64 + r * 16 + quad * 4 + i;
      u64 kmin = ~0ull;
      #pragma unroll
      for (int c = 0; c < 4; ++c) {
        int gcol = col0 + wc * 64 + c * 16 + lcol;
        float d = __fadd_rn(e2v[c], __fmul_rn(-2.0f, acc[r][c][i]));
        dist[(size_t)grow * ENUM_ + gcol] = d;
        u64 key = ((u64)sortable(d) << 32) | (u32)gcol;
        kmin = key < kmin ? key : kmin;
      }
      #pragma unroll
      for (int msk = 1; msk < 16; msk <<= 1) {
        u64 o = __shfl_xor(kmin, msk);
        kmin = o < kmin ? o : kmin;
      }
      if (lcol == 0) atomicMin(&best[grow], kmin);
    }
  }
}

// ---------- pass 2: scan d-hat, emit candidates within margin of row min ----
__global__ __launch_bounds__(256)
void scan_kernel(const float* __restrict__ dist, const u64* __restrict__ best,
                 u64* __restrict__ cand, int* __restrict__ ccount) {
  const int n4 = BROWS * ENUM_ / 4;
  int step = gridDim.x * 256;
  for (int f = blockIdx.x * 256 + threadIdx.x; f < n4; f += step) {
    int i = f >> 12;                       // 4096 float4 per row
    float limit = unsortable((u32)(best[i] >> 32)) + MARGIN;
    float4 v = ((const float4*)dist)[f];
    float dv[4] = {v.x, v.y, v.z, v.w};
    #pragma unroll
    for (int e = 0; e < 4; ++e) {
      if (dv[e] <= limit) {
        int pos = atomicAdd(ccount, 1);
        if (pos < CANDMAX) cand[pos] = ((u64)(u32)i << 32) | (u32)(f * 4 + e - i * ENUM_);
      }
    }
  }
}

// ---------- pass 3: exact fp64 rescore of candidates ----------
__global__ __launch_bounds__(256)
void refine_kernel(const float* __restrict__ x, const float* __restrict__ w,
                   const u64* __restrict__ cand, const int* __restrict__ ccount,
                   u64* __restrict__ best2) {
  int cnt = *ccount;
  if (cnt > CANDMAX) cnt = CANDMAX;
  for (int b = blockIdx.x; b < cnt; b += gridDim.x) {
    u64 cd = cand[b];
    int i = (int)(cd >> 32), j = (int)(cd & 0xffffffffu);
    const float4* xr = (const float4*)(x + (size_t)i * KD);
    const float4* wr = (const float4*)(w + (size_t)j * KD);
    double local = 0.0;
    #pragma unroll
    for (int t = 0; t < 4; ++t) {
      int e = threadIdx.x + t * 256;
      float4 xv = xr[e], wv = wr[e];
      // d = sum w*(w - 2x)
      local += (double)wv.x * ((double)wv.x - 2.0 * (double)xv.x)
             + (double)wv.y * ((double)wv.y - 2.0 * (double)xv.y)
             + (double)wv.z * ((double)wv.z - 2.0 * (double)xv.z)
             + (double)wv.w * ((double)wv.w - 2.0 * (double)xv.w);
    }
    double d = blockReduceSumD(local);
    if (threadIdx.x == 0) {
      u64 key = ((u64)sortable((float)d) << 32) | (u32)j;
      atomicMin(&best2[i], key);
    }
    __syncthreads();  // protect shared reuse across persistent iterations
  }
}

// ---------- 3-term fallback GEMM (round-2 kernel) ----------
__global__ __launch_bounds__(256)
void gemm_argmin_mfma(const u16* __restrict__ Ah, const u16* __restrict__ Al,
                      const u16* __restrict__ Bh, const u16* __restrict__ Bl,
                      const float* __restrict__ e2, u64* __restrict__ best) {
  __shared__ char smem[32768];
  const int by = blockIdx.x, bx = blockIdx.y;
  const int row0 = by * 128, col0 = bx * 128;
  const int t = threadIdx.x;
  const int lane = t & 63, wv = t >> 6;
  const int wr = wv >> 1, wc = wv & 1;
  const int srow = t >> 2;
  const int schunk = (t & 3) ^ ((t >> 3) & 3);
  const size_t aoff0 = (size_t)(row0 + srow) * KD + schunk * 8;
  const size_t aoff1 = aoff0 + (size_t)64 * KD;
  const size_t boff0 = (size_t)(col0 + srow) * KD + schunk * 8;
  const size_t boff1 = boff0 + (size_t)64 * KD;
  char* sAh = smem; char* sAl = smem + 8192;
  char* sBh = smem + 16384; char* sBl = smem + 24576;
  const int d0 = t * 16, d1 = 4096 + t * 16;
  floatx4 acc[4][4] = {};
  for (int kk = 0; kk < KD; kk += 32) {
    __syncthreads();
    gload_lds16(Ah + aoff0 + kk, sAh + d0);
    gload_lds16(Ah + aoff1 + kk, sAh + d1);
    gload_lds16(Al + aoff0 + kk, sAl + d0);
    gload_lds16(Al + aoff1 + kk, sAl + d1);
    gload_lds16(Bh + boff0 + kk, sBh + d0);
    gload_lds16(Bh + boff1 + kk, sBh + d1);
    gload_lds16(Bl + boff0 + kk, sBl + d0);
    gload_lds16(Bl + boff1 + kk, sBl + d1);
    __syncthreads();
    short8 afh[4], afl[4];
    #pragma unroll
    for (int r = 0; r < 4; ++r) {
      int m = wr * 64 + r * 16 + (lane & 15);
      int off = m * 64 + (((lane >> 4) ^ ((m >> 1) & 3)) * 16);
      afh[r] = *(const short8*)(sAh + off);
      afl[r] = *(const short8*)(sAl + off);
    }
    #pragma unroll
    for (int c = 0; c < 4; ++c) {
      int m = wc * 64 + c * 16 + (lane & 15);
      int off = m * 64 + (((lane >> 4) ^ ((m >> 1) & 3)) * 16);
      short8 bfh = *(const short8*)(sBh + off);
      short8 bfl = *(const short8*)(sBl + off);
      #pragma unroll
      for (int r = 0; r < 4; ++r) {
        acc[r][c] = __builtin_amdgcn_mfma_f32_16x16x32_bf16(afh[r], bfh, acc[r][c], 0, 0, 0);
        acc[r][c] = __builtin_amdgcn_mfma_f32_16x16x32_bf16(afl[r], bfh, acc[r][c], 0, 0, 0);
        acc[r][c] = __builtin_amdgcn_mfma_f32_16x16x32_bf16(afh[r], bfl, acc[r][c], 0, 0, 0);
      }
    }
  }
  const int quad = lane >> 4, lcol = lane & 15;
  float e2v[4];
  #pragma unroll
  for (int c = 0; c < 4; ++c) e2v[c] = e2[col0 + wc * 64 + c * 16 + lcol];
  #pragma unroll
  for (int r = 0; r < 4; ++r) {
    #pragma unroll
    for (int i = 0; i < 4; ++i) {
      int grow = row0 + wr * 64 + r * 16 + quad * 4 + i;
      u64 kmin = ~0ull;
      #pragma unroll
      for (int c = 0; c < 4; ++c) {
        int gcol = col0 + wc * 64 + c * 16 + lcol;
        float d = __fadd_rn(e2v[c], __fmul_rn(-2.0f, acc[r][c][i]));
        u64 key = ((u64)sortable(d) << 32) | (u32)gcol;
        kmin = key < kmin ? key : kmin;
      }
      #pragma unroll
      for (int msk = 1; msk < 16; msk <<= 1) {
        u64 o = __shfl_xor(kmin, msk);
        kmin = o < kmin ? o : kmin;
      }
      if (lcol == 0) atomicMin(&best[grow], kmin);
    }
  }
}

// ---------- fp32 fallback GEMM (round-1 kernel) ----------
__global__ __launch_bounds__(256)
void gemm_argmin(const float* __restrict__ A, const float* __restrict__ W,
                 const float* __restrict__ e2, u64* __restrict__ best) {
  __shared__ union {
    struct { float As[8][128]; float Bs[8][128]; } st;
    u64 red[128 * 16];
  } sm;
  const int by = blockIdx.x, bx = blockIdx.y;
  const int tid = threadIdx.x;
  const int tx = tid & 15, ty = tid >> 4;
  const int row0 = by * 128, col0 = bx * 128;
  const int lm = tid >> 1, lk = (tid & 1) * 4;
  const float* Ap = A + (size_t)(row0 + lm) * KD + lk;
  const float* Wp = W + (size_t)(col0 + lm) * KD + lk;
  float acc[8][8];
  #pragma unroll
  for (int r = 0; r < 8; ++r)
    #pragma unroll
    for (int c = 0; c < 8; ++c) acc[r][c] = 0.f;
  for (int kk = 0; kk < KD; kk += 8) {
    float4 av = *(const float4*)(Ap + kk);
    float4 bv = *(const float4*)(Wp + kk);
    __syncthreads();
    sm.st.As[lk + 0][lm] = av.x; sm.st.As[lk + 1][lm] = av.y;
    sm.st.As[lk + 2][lm] = av.z; sm.st.As[lk + 3][lm] = av.w;
    sm.st.Bs[lk + 0][lm] = bv.x; sm.st.Bs[lk + 1][lm] = bv.y;
    sm.st.Bs[lk + 2][lm] = bv.z; sm.st.Bs[lk + 3][lm] = bv.w;
    __syncthreads();
    #pragma unroll
    for (int k = 0; k < 8; ++k) {
      float a[8], b[8];
      *(float4*)&a[0] = *(const float4*)&sm.st.As[k][ty * 8];
      *(float4*)&a[4] = *(const float4*)&sm.st.As[k][ty * 8 + 4];
      *(float4*)&b[0] = *(const float4*)&sm.st.Bs[k][tx * 8];
      *(float4*)&b[4] = *(const float4*)&sm.st.Bs[k][tx * 8 + 4];
      #pragma unroll
      for (int r = 0; r < 8; ++r)
        #pragma unroll
        for (int c = 0; c < 8; ++c)
          acc[r][c] = fmaf(a[r], b[c], acc[r][c]);
    }
  }
  __syncthreads();
  float e2v[8];
  #pragma unroll
  for (int c = 0; c < 8; ++c) e2v[c] = e2[col0 + tx * 8 + c];
  #pragma unroll
  for (int r = 0; r < 8; ++r) {
    u64 bk = ~0ull;
    #pragma unroll
    for (int c = 0; c < 8; ++c) {
      int col = col0 + tx * 8 + c;
      float d = fmaf(-2.0f, acc[r][c], e2v[c]);
      u64 key = ((u64)sortable(d) << 32) | (u32)col;
      bk = key < bk ? key : bk;
    }
    sm.red[(ty * 8 + r) * 16 + tx] = bk;
  }
  __syncthreads();
  if (tid < 128) {
    u64 m = sm.red[tid * 16];
    #pragma unroll
    for (int t2 = 1; t2 < 16; ++t2) {
      u64 v = sm.red[tid * 16 + t2];
      m = v < m ? v : m;
    }
    atomicMin(&best[row0 + tid], m);
  }
}

// ---------- tail kernels ----------

__global__ __launch_bounds__(256) void scatter_kernel(const u64* __restrict__ best,
                                                      int* __restrict__ idx,
                                                      int* __restrict__ counts,
                                                      float* __restrict__ enc) {
  int i = blockIdx.x * 256 + threadIdx.x;
  u64 k = best[i];
  int j = (int)(k & 0xffffffffu);
  idx[i] = j;
  atomicAdd(&counts[j], 1);
  enc[(size_t)i * ENUM_ + j] = 1.0f;
}

__global__ __launch_bounds__(256) void gather_loss(const float* __restrict__ x,
                                                   const float* __restrict__ w,
                                                   const int* __restrict__ idx,
                                                   float* __restrict__ quant,
                                                   double* __restrict__ accum) {
  int i = blockIdx.x;
  int j = idx[i];
  const float4* wr = (const float4*)(w + (size_t)j * KD);
  const float4* xr = (const float4*)(x + (size_t)i * KD);
  float* qr = quant + (size_t)i * KD;
  double local = 0.0;
  #pragma unroll
  for (int t = 0; t < 4; ++t) {
    int e = threadIdx.x + t * 256;
    float4 wv = wr[e];
    float4 xv = xr[e];
    qr[4 * e + 0] = wv.x; qr[4 * e + 1] = wv.y;
    qr[4 * e + 2] = wv.z; qr[4 * e + 3] = wv.w;
    double d0 = (double)wv.x - (double)xv.x;
    double d1 = (double)wv.y - (double)xv.y;
    double d2 = (double)wv.z - (double)xv.z;
    double d3 = (double)wv.w - (double)xv.w;
    local += d0 * d0 + d1 * d1 + d2 * d2 + d3 * d3;
  }
  double tot = blockReduceSumD(local);
  if (threadIdx.x == 0) atomicAdd(accum, tot);
}

__global__ __launch_bounds__(256) void scalars_kernel(const int* __restrict__ counts,
                                                      const double* __restrict__ accum,
                                                      float* __restrict__ loss_out,
                                                      float* __restrict__ perp_out) {
  double local = 0.0;
  for (int j = threadIdx.x; j < ENUM_; j += 256) {
    double p = (double)counts[j] * (1.0 / 4096.0);
    local += p * log(p + 1e-10);
  }
  double s = blockReduceSumD(local);
  if (threadIdx.x == 0) {
    double mean = (*accum) * (1.0 / ((double)BROWS * (double)KD));
    loss_out[0] = (float)(1.25 * mean);
    perp_out[0] = (float)exp(-s);
  }
}

// ---------- launch ----------

extern "C" void kernel_launch(void* const* d_in, const int* in_sizes, int n_in,
                              void* d_out, int out_size, void* d_ws, size_t ws_size,
                              hipStream_t stream) {
  const float* x = (const float*)d_in[0];  // [4096][4096]
  const float* w = (const float*)d_in[1];  // [16384][4096]
  float* out = (float*)d_out;

  char* ws = (char*)d_ws;
  u64* best     = (u64*)ws;                    // 32768
  u64* best2    = (u64*)(ws + 32768);          // 32768
  int* idx      = (int*)(ws + 65536);          // 16384
  int* counts   = (int*)(ws + 81920);          // 65536
  double* accum = (double*)(ws + 147456);      // 8
  int* ccount   = (int*)(ws + 147464);         // 4
  float* e2     = (float*)(ws + 163840);       // 65536
  u64* cand     = (u64*)(ws + 229376);         // 524288
  u16* x_hi     = (u16*)(ws + 753664);                 // 33554432
  u16* w_hi     = (u16*)(ws + 753664 + 33554432ull);   // 134217728
  char* regionR = ws + 753664 + 33554432ull + 134217728ull;  // 168525824
  float* dist   = (float*)regionR;             // 268435456 (filter-refine)
  u16* x_lo     = (u16*)regionR;               // 33554432  (3-term fallback)
  u16* w_lo     = (u16*)(regionR + 33554432ull);       // 134217728
  const size_t NEED_FR = 168525824ull + 268435456ull;  // ~437 MB
  const size_t NEED_3T = 168525824ull + 167772160ull;  // ~336 MB

  float* loss_out = out;
  float* quant    = out + 1;
  float* perp_out = out + 16777217;
  float* enc      = out + 16777218;

  hipMemsetAsync(best, 0xFF, 65536, stream);            // best + best2
  hipMemsetAsync(counts, 0, 65536 + 16, stream);        // counts + accum + ccount
  hipMemsetAsync(enc, 0, (size_t)BROWS * ENUM_ * sizeof(float), stream);

  if (ws_size >= NEED_FR) {
    split_hi<<<BROWS * KD / 8 / 256, 256, 0, stream>>>(x, x_hi, BROWS * KD / 8);
    split_w_e2<<<ENUM_, 256, 0, stream>>>(w, w_hi, e2);
    gemm_hi<<<dim3(32, 128), 256, 0, stream>>>(x_hi, w_hi, e2, dist, best);
    scan_kernel<<<4096, 256, 0, stream>>>(dist, best, cand, ccount);
    refine_kernel<<<4096, 256, 0, stream>>>(x, w, cand, ccount, best2);
    scatter_kernel<<<BROWS / 256, 256, 0, stream>>>(best2, idx, counts, enc);
  } else if (ws_size >= NEED_3T) {
    e2_kernel<<<ENUM_, 256, 0, stream>>>(w, e2);
    split_kernel<<<BROWS * KD / 8 / 256, 256, 0, stream>>>(x, x_hi, x_lo, BROWS * KD / 8);
    split_kernel<<<ENUM_ * KD / 8 / 256, 256, 0, stream>>>(w, w_hi, w_lo, ENUM_ * KD / 8);
    gemm_argmin_mfma<<<dim3(32, 128), 256, 0, stream>>>(x_hi, x_lo, w_hi, w_lo, e2, best);
    scatter_kernel<<<BROWS / 256, 256, 0, stream>>>(best, idx, counts, enc);
  } else {
    e2_kernel<<<ENUM_, 256, 0, stream>>>(w, e2);
    gemm_argmin<<<dim3(32, 128), 256, 0, stream>>>(x, w, e2, best);
    scatter_kernel<<<BROWS / 256, 256, 0, stream>>>(best, idx, counts, enc);
  }
  gather_loss<<<BROWS, 256, 0, stream>>>(x, w, idx, quant, accum);
  scalars_kernel<<<1, 256, 0, stream>>>(counts, accum, loss_out, perp_out);
}